// Round 1
// baseline (1041.676 us; speedup 1.0000x reference)
//
#include <hip/hip_runtime.h>
#include <math.h>

// ---------------------------------------------------------------------------
// GCN 3-layer forward on MI355X.
// Layers: h = relu(gcnconv(x, W1,b1)); h = relu(gcnconv(h, W2,b2)); out = gcnconv(h, W3,b3)
// gcnconv: xw = h@W; deg = segsum(w,dst)+1; dinv = rsqrt(deg);
//          out = segsum(dinv[src]*w*dinv[dst] * xw[src], dst) + dinv^2*xw + b
// Strategy: build CSR (by dst) once per launch; fp32 tiled GEMM (no MFMA —
// bf16 would blow the 1.2e-3 absmax threshold); gather-style aggregation.
// ---------------------------------------------------------------------------

__global__ __launch_bounds__(256) void init_kernel(float* deg, int* counts, int* fillc, int n) {
  int i = blockIdx.x * 256 + threadIdx.x;
  if (i < n) { deg[i] = 1.0f; counts[i] = 0; fillc[i] = 0; }
}

__global__ __launch_bounds__(256) void edge_deg_kernel(const int* __restrict__ ei,
    const float* __restrict__ ew, float* __restrict__ deg, int* __restrict__ counts, int E) {
  int e = blockIdx.x * 256 + threadIdx.x;
  if (e >= E) return;
  int d = ei[E + e];               // dst row of edge_index
  atomicAdd(&deg[d], ew[e]);
  atomicAdd(&counts[d], 1);
}

__global__ __launch_bounds__(256) void dinv_kernel(float* deg, int n) {
  int i = blockIdx.x * 256 + threadIdx.x;
  if (i < n) deg[i] = 1.0f / sqrtf(deg[i]);   // deg >= 1 always (self-loop weight 1)
}

// ---- 3-kernel exclusive scan of counts -> row_ptr --------------------------
__global__ __launch_bounds__(1024) void scanA(const int* __restrict__ counts,
    int* __restrict__ row_ptr, int* __restrict__ partials, int n) {
  __shared__ int sd[1024];
  int t = threadIdx.x;
  int i = blockIdx.x * 1024 + t;
  int v = (i < n) ? counts[i] : 0;
  sd[t] = v;
  __syncthreads();
  for (int off = 1; off < 1024; off <<= 1) {
    int u = (t >= off) ? sd[t - off] : 0;
    __syncthreads();
    sd[t] += u;
    __syncthreads();
  }
  int incl = sd[t];
  if (i < n) row_ptr[i] = incl - v;           // block-local exclusive
  if (t == 1023) partials[blockIdx.x] = incl; // block total
}

__global__ __launch_bounds__(128) void scanB(int* partials, int nb) {
  __shared__ int sd[128];
  int t = threadIdx.x;
  int v = (t < nb) ? partials[t] : 0;
  sd[t] = v;
  __syncthreads();
  for (int off = 1; off < 128; off <<= 1) {
    int u = (t >= off) ? sd[t - off] : 0;
    __syncthreads();
    sd[t] += u;
    __syncthreads();
  }
  int incl = sd[t];
  partials[t] = incl - v;                     // exclusive block offsets
  if (t == nb - 1) partials[255] = incl;      // grand total -> slot 255
}

__global__ __launch_bounds__(1024) void scanC(int* row_ptr, const int* __restrict__ partials, int n) {
  int i = blockIdx.x * 1024 + threadIdx.x;
  if (i < n) row_ptr[i] += partials[blockIdx.x];
  if (i == 0) row_ptr[n] = partials[255];
}

__global__ __launch_bounds__(256) void fill_kernel(const int* __restrict__ ei,
    const float* __restrict__ ew, const float* __restrict__ dinv,
    const int* __restrict__ row_ptr, int* __restrict__ fillc,
    int* __restrict__ ssrc, float* __restrict__ snorm, int E) {
  int e = blockIdx.x * 256 + threadIdx.x;
  if (e >= E) return;
  int s = ei[e], d = ei[E + e];
  float nw = dinv[s] * ew[e] * dinv[d];
  int p = row_ptr[d] + atomicAdd(&fillc[d], 1);
  ssrc[p] = s;
  snorm[p] = nw;
}

// ---- fp32 GEMM: C[M,N] = A[M,128] @ W[128,N], N in {64,128} ----------------
// 64x64 tile, full K=128 staged in LDS (exactly 64KB -> 2 blocks/CU).
// A tile is XOR-swizzled so the 4-row float4 reads hit 4 distinct banks.
__device__ __forceinline__ int aswz(int r, int k) {
  int kv = (k >> 2) ^ (((r >> 2) & 7) << 1);
  return r * 128 + (kv << 2) + (k & 3);
}

__global__ __launch_bounds__(256) void gemm_kernel(const float* __restrict__ A,
    const float* __restrict__ W, float* __restrict__ C, int M, int N) {
  __shared__ float AsF[64 * 128];   // 32 KB, swizzled [row][k]
  __shared__ float Ws[128][64];     // 32 KB
  int t = threadIdx.x;
  int row0 = blockIdx.x * 64;
  int col0 = blockIdx.y * 64;
  {
    int k = t & 127, r0 = t >> 7;   // 128 lanes span k; 2 rows per pass
#pragma unroll
    for (int r = r0; r < 64; r += 2) {
      int m = row0 + r;
      AsF[aswz(r, k)] = (m < M) ? A[(size_t)m * 128 + k] : 0.0f;
    }
  }
  {
    int c = t & 63, k0 = t >> 6;    // 64 lanes span cols; 4 k-rows per pass
#pragma unroll
    for (int k = k0; k < 128; k += 4) {
      Ws[k][c] = W[k * N + col0 + c];
    }
  }
  __syncthreads();
  int tx = t & 15, ty = t >> 4;     // 16x16 threads, 4x4 micro-tile each
  float acc[4][4] = {};
#pragma unroll 8
  for (int k = 0; k < 128; k += 4) {
    float4 a[4], w[4];
#pragma unroll
    for (int i = 0; i < 4; i++) a[i] = *(const float4*)&AsF[aswz(ty * 4 + i, k)];
#pragma unroll
    for (int kk = 0; kk < 4; kk++) w[kk] = *(const float4*)&Ws[k + kk][tx * 4];
#pragma unroll
    for (int i = 0; i < 4; i++) {
      float av[4] = {a[i].x, a[i].y, a[i].z, a[i].w};
#pragma unroll
      for (int kk = 0; kk < 4; kk++) {
        acc[i][0] = fmaf(av[kk], w[kk].x, acc[i][0]);
        acc[i][1] = fmaf(av[kk], w[kk].y, acc[i][1]);
        acc[i][2] = fmaf(av[kk], w[kk].z, acc[i][2]);
        acc[i][3] = fmaf(av[kk], w[kk].w, acc[i][3]);
      }
    }
  }
#pragma unroll
  for (int i = 0; i < 4; i++) {
    int m = row0 + ty * 4 + i;
    if (m < M) {
      float4 v = make_float4(acc[i][0], acc[i][1], acc[i][2], acc[i][3]);
      *(float4*)&C[(size_t)m * N + col0 + tx * 4] = v;
    }
  }
}

// ---- aggregation: out[n] = sum_{e: dst=n} norm_e * xw[src_e] + dinv^2*xw[n] + b
template <int F, bool RELU>
__global__ __launch_bounds__(256) void agg_kernel(const float* __restrict__ xw,
    const int* __restrict__ row_ptr, const int* __restrict__ ssrc,
    const float* __restrict__ snorm, const float* __restrict__ dinv,
    const float* __restrict__ bias, float* __restrict__ out, int Nn) {
  constexpr int LPN = F / 4;                  // lanes per node (float4 each)
  int t = blockIdx.x * 256 + threadIdx.x;
  int node = t / LPN;
  int lane = t % LPN;
  if (node >= Nn) return;
  const float4* xw4 = (const float4*)xw;
  int start = row_ptr[node];
  int end = row_ptr[node + 1];
  float ax = 0.f, ay = 0.f, az = 0.f, aw = 0.f;
  for (int p = start; p < end; ++p) {
    int s = ssrc[p];
    float nw = snorm[p];
    float4 v = xw4[(size_t)s * LPN + lane];
    ax = fmaf(nw, v.x, ax); ay = fmaf(nw, v.y, ay);
    az = fmaf(nw, v.z, az); aw = fmaf(nw, v.w, aw);
  }
  float di = dinv[node];
  float sw = di * di;
  float4 sv = xw4[(size_t)node * LPN + lane];
  ax = fmaf(sw, sv.x, ax); ay = fmaf(sw, sv.y, ay);
  az = fmaf(sw, sv.z, az); aw = fmaf(sw, sv.w, aw);
  float4 b = ((const float4*)bias)[lane];
  ax += b.x; ay += b.y; az += b.z; aw += b.w;
  if (RELU) {
    ax = fmaxf(ax, 0.f); ay = fmaxf(ay, 0.f);
    az = fmaxf(az, 0.f); aw = fmaxf(aw, 0.f);
  }
  ((float4*)out)[(size_t)node * LPN + lane] = make_float4(ax, ay, az, aw);
}

// ---------------------------------------------------------------------------
extern "C" void kernel_launch(void* const* d_in, const int* in_sizes, int n_in,
                              void* d_out, int out_size, void* d_ws, size_t ws_size,
                              hipStream_t stream) {
  const float* x  = (const float*)d_in[0];
  const int*   ei = (const int*)d_in[1];     // int32 (JAX default x64 off), [2,E] flat
  const float* ew = (const float*)d_in[2];
  const float* W1 = (const float*)d_in[3];
  const float* b1 = (const float*)d_in[4];
  const float* W2 = (const float*)d_in[5];
  const float* b2 = (const float*)d_in[6];
  const float* W3 = (const float*)d_in[7];
  const float* b3 = (const float*)d_in[8];

  const int N = in_sizes[0] / 128;           // 100000
  const int E = in_sizes[2];                 // 1600000

  // workspace carve (256B aligned)
  char* ws = (char*)d_ws;
  size_t off = 0;
  auto carve = [&](size_t bytes) -> void* {
    void* p = ws + off;
    off += (bytes + 255) & ~(size_t)255;
    return p;
  };
  float* dinv    = (float*)carve((size_t)N * 4);        // deg -> dinv in place
  int*   counts  = (int*)carve((size_t)N * 4);
  int*   fillc   = (int*)carve((size_t)N * 4);
  int*   row_ptr = (int*)carve((size_t)(N + 1) * 4);
  int*   parts   = (int*)carve(256 * 4);
  int*   ssrc    = (int*)carve((size_t)E * 4);
  float* snorm   = (float*)carve((size_t)E * 4);
  float* bufA    = (float*)carve((size_t)N * 128 * 4);
  float* bufB    = (float*)carve((size_t)N * 128 * 4);
  (void)ws_size; (void)n_in; (void)out_size;

  const int nThreads = 256;
  int gN  = (N + nThreads - 1) / nThreads;
  int gE  = (E + nThreads - 1) / nThreads;
  int nb  = (N + 1023) / 1024;               // scan blocks (98)

  // --- graph preprocessing (shared across the 3 layers) ---
  init_kernel<<<gN, nThreads, 0, stream>>>(dinv, counts, fillc, N);
  edge_deg_kernel<<<gE, nThreads, 0, stream>>>(ei, ew, dinv, counts, E);
  dinv_kernel<<<gN, nThreads, 0, stream>>>(dinv, N);
  scanA<<<nb, 1024, 0, stream>>>(counts, row_ptr, parts, N);
  scanB<<<1, 128, 0, stream>>>(parts, nb);
  scanC<<<nb, 1024, 0, stream>>>(row_ptr, parts, N);
  fill_kernel<<<gE, nThreads, 0, stream>>>(ei, ew, dinv, row_ptr, fillc, ssrc, snorm, E);

  const int gM = (N + 63) / 64;              // 1563 row-blocks
  int gAgg128 = (N * 32 + nThreads - 1) / nThreads;
  int gAgg64  = (N * 16 + nThreads - 1) / nThreads;

  // --- layer 1: xw1 = x@W1 -> bufA; aggregate+bias+relu -> bufB ---
  gemm_kernel<<<dim3(gM, 2), nThreads, 0, stream>>>(x, W1, bufA, N, 128);
  agg_kernel<128, true><<<gAgg128, nThreads, 0, stream>>>(bufA, row_ptr, ssrc, snorm, dinv, b1, bufB, N);

  // --- layer 2: xw2 = h1@W2 -> bufA; aggregate+bias+relu -> bufB ---
  gemm_kernel<<<dim3(gM, 2), nThreads, 0, stream>>>(bufB, W2, bufA, N, 128);
  agg_kernel<128, true><<<gAgg128, nThreads, 0, stream>>>(bufA, row_ptr, ssrc, snorm, dinv, b2, bufB, N);

  // --- layer 3: xw3 = h2@W3 -> bufA; aggregate+bias (no relu) -> d_out ---
  gemm_kernel<<<dim3(gM, 1), nThreads, 0, stream>>>(bufB, W3, bufA, N, 64);
  agg_kernel<64, false><<<gAgg64, nThreads, 0, stream>>>(bufA, row_ptr, ssrc, snorm, dinv, b3, (float*)d_out, N);
}

// Round 2
// 812.811 us; speedup vs baseline: 1.2816x; 1.2816x over previous
//
#include <hip/hip_runtime.h>
#include <math.h>

// ---------------------------------------------------------------------------
// GCN 3-layer forward on MI355X.
// Round 1 change: GEMM rewritten. Old 64x64-tile version was LDS-read-bound
// (0.5 FMA/LDS-byte vs 1.0 needed; VALUBusy 16%, 235us/dispatch). New version:
// W slice (128x64, 32KB) in LDS read as wave-uniform BROADCASTS (free BW);
// A row per thread in registers; 64-wide fp32 accumulator per thread.
// ---------------------------------------------------------------------------

__global__ __launch_bounds__(256) void init_kernel(float* deg, int* counts, int* fillc, int n) {
  int i = blockIdx.x * 256 + threadIdx.x;
  if (i < n) { deg[i] = 1.0f; counts[i] = 0; fillc[i] = 0; }
}

__global__ __launch_bounds__(256) void edge_deg_kernel(const int* __restrict__ ei,
    const float* __restrict__ ew, float* __restrict__ deg, int* __restrict__ counts, int E) {
  int e = blockIdx.x * 256 + threadIdx.x;
  if (e >= E) return;
  int d = ei[E + e];               // dst row of edge_index
  atomicAdd(&deg[d], ew[e]);
  atomicAdd(&counts[d], 1);
}

__global__ __launch_bounds__(256) void dinv_kernel(float* deg, int n) {
  int i = blockIdx.x * 256 + threadIdx.x;
  if (i < n) deg[i] = 1.0f / sqrtf(deg[i]);   // deg >= 1 always (self-loop weight 1)
}

// ---- 3-kernel exclusive scan of counts -> row_ptr --------------------------
__global__ __launch_bounds__(1024) void scanA(const int* __restrict__ counts,
    int* __restrict__ row_ptr, int* __restrict__ partials, int n) {
  __shared__ int sd[1024];
  int t = threadIdx.x;
  int i = blockIdx.x * 1024 + t;
  int v = (i < n) ? counts[i] : 0;
  sd[t] = v;
  __syncthreads();
  for (int off = 1; off < 1024; off <<= 1) {
    int u = (t >= off) ? sd[t - off] : 0;
    __syncthreads();
    sd[t] += u;
    __syncthreads();
  }
  int incl = sd[t];
  if (i < n) row_ptr[i] = incl - v;           // block-local exclusive
  if (t == 1023) partials[blockIdx.x] = incl; // block total
}

__global__ __launch_bounds__(128) void scanB(int* partials, int nb) {
  __shared__ int sd[128];
  int t = threadIdx.x;
  int v = (t < nb) ? partials[t] : 0;
  sd[t] = v;
  __syncthreads();
  for (int off = 1; off < 128; off <<= 1) {
    int u = (t >= off) ? sd[t - off] : 0;
    __syncthreads();
    sd[t] += u;
    __syncthreads();
  }
  int incl = sd[t];
  partials[t] = incl - v;                     // exclusive block offsets
  if (t == nb - 1) partials[255] = incl;      // grand total -> slot 255
}

__global__ __launch_bounds__(1024) void scanC(int* row_ptr, const int* __restrict__ partials, int n) {
  int i = blockIdx.x * 1024 + threadIdx.x;
  if (i < n) row_ptr[i] += partials[blockIdx.x];
  if (i == 0) row_ptr[n] = partials[255];
}

__global__ __launch_bounds__(256) void fill_kernel(const int* __restrict__ ei,
    const float* __restrict__ ew, const float* __restrict__ dinv,
    const int* __restrict__ row_ptr, int* __restrict__ fillc,
    int* __restrict__ ssrc, float* __restrict__ snorm, int E) {
  int e = blockIdx.x * 256 + threadIdx.x;
  if (e >= E) return;
  int s = ei[e], d = ei[E + e];
  float nw = dinv[s] * ew[e] * dinv[d];
  int p = row_ptr[d] + atomicAdd(&fillc[d], 1);
  ssrc[p] = s;
  snorm[p] = nw;
}

// ---- fp32 GEMM, row-per-thread: C[M,N] = A[M,128] @ W[128,N] ---------------
// Block = 256 threads = 256 rows; blockIdx.y selects a 64-column slice of W.
// W slice staged in 32KB LDS, read as wave-uniform broadcasts (no LDS BW
// cost). A row streamed float4 from global (L3-resident). acc[64] in VGPRs.
template <int NCOL>
__global__ __launch_bounds__(256) void gemm_rows_kernel(const float* __restrict__ A,
    const float* __restrict__ W, float* __restrict__ C, int M, int N) {
  __shared__ float Ws[128][NCOL];
  const int col0 = blockIdx.y * NCOL;
  for (int i = threadIdx.x; i < 128 * NCOL / 4; i += 256) {
    int k = i / (NCOL / 4);
    int c4 = i % (NCOL / 4);
    *(float4*)&Ws[k][c4 * 4] = *(const float4*)&W[k * N + col0 + c4 * 4];
  }
  __syncthreads();
  int r = blockIdx.x * 256 + threadIdx.x;
  if (r >= M) return;
  const float4* a4 = (const float4*)(A + (size_t)r * 128);
  float acc[NCOL] = {};
  float4 a = a4[0];
#pragma unroll 1
  for (int k4 = 0; k4 < 32; k4++) {
    float4 cur = a;
    if (k4 < 31) a = a4[k4 + 1];            // prefetch next A chunk
    float av[4] = {cur.x, cur.y, cur.z, cur.w};
#pragma unroll
    for (int kk = 0; kk < 4; kk++) {
      const float* wrow = &Ws[k4 * 4 + kk][0];
#pragma unroll
      for (int c = 0; c < NCOL; c++)
        acc[c] = fmaf(av[kk], wrow[c], acc[c]);
    }
  }
  float* crow = C + (size_t)r * N + col0;
#pragma unroll
  for (int c = 0; c < NCOL; c += 4)
    *(float4*)&crow[c] = make_float4(acc[c], acc[c + 1], acc[c + 2], acc[c + 3]);
}

// ---- aggregation: out[n] = sum_{e: dst=n} norm_e * xw[src_e] + dinv^2*xw[n] + b
template <int F, bool RELU>
__global__ __launch_bounds__(256) void agg_kernel(const float* __restrict__ xw,
    const int* __restrict__ row_ptr, const int* __restrict__ ssrc,
    const float* __restrict__ snorm, const float* __restrict__ dinv,
    const float* __restrict__ bias, float* __restrict__ out, int Nn) {
  constexpr int LPN = F / 4;                  // lanes per node (float4 each)
  int t = blockIdx.x * 256 + threadIdx.x;
  int node = t / LPN;
  int lane = t % LPN;
  if (node >= Nn) return;
  const float4* xw4 = (const float4*)xw;
  int start = row_ptr[node];
  int end = row_ptr[node + 1];
  float ax = 0.f, ay = 0.f, az = 0.f, aw = 0.f;
  for (int p = start; p < end; ++p) {
    int s = ssrc[p];
    float nw = snorm[p];
    float4 v = xw4[(size_t)s * LPN + lane];
    ax = fmaf(nw, v.x, ax); ay = fmaf(nw, v.y, ay);
    az = fmaf(nw, v.z, az); aw = fmaf(nw, v.w, aw);
  }
  float di = dinv[node];
  float sw = di * di;
  float4 sv = xw4[(size_t)node * LPN + lane];
  ax = fmaf(sw, sv.x, ax); ay = fmaf(sw, sv.y, ay);
  az = fmaf(sw, sv.z, az); aw = fmaf(sw, sv.w, aw);
  float4 b = ((const float4*)bias)[lane];
  ax += b.x; ay += b.y; az += b.z; aw += b.w;
  if (RELU) {
    ax = fmaxf(ax, 0.f); ay = fmaxf(ay, 0.f);
    az = fmaxf(az, 0.f); aw = fmaxf(aw, 0.f);
  }
  ((float4*)out)[(size_t)node * LPN + lane] = make_float4(ax, ay, az, aw);
}

// ---------------------------------------------------------------------------
extern "C" void kernel_launch(void* const* d_in, const int* in_sizes, int n_in,
                              void* d_out, int out_size, void* d_ws, size_t ws_size,
                              hipStream_t stream) {
  const float* x  = (const float*)d_in[0];
  const int*   ei = (const int*)d_in[1];     // int32, [2,E] flat
  const float* ew = (const float*)d_in[2];
  const float* W1 = (const float*)d_in[3];
  const float* b1 = (const float*)d_in[4];
  const float* W2 = (const float*)d_in[5];
  const float* b2 = (const float*)d_in[6];
  const float* W3 = (const float*)d_in[7];
  const float* b3 = (const float*)d_in[8];

  const int N = in_sizes[0] / 128;           // 100000
  const int E = in_sizes[2];                 // 1600000

  // workspace carve (256B aligned)
  char* ws = (char*)d_ws;
  size_t off = 0;
  auto carve = [&](size_t bytes) -> void* {
    void* p = ws + off;
    off += (bytes + 255) & ~(size_t)255;
    return p;
  };
  float* dinv    = (float*)carve((size_t)N * 4);        // deg -> dinv in place
  int*   counts  = (int*)carve((size_t)N * 4);
  int*   fillc   = (int*)carve((size_t)N * 4);
  int*   row_ptr = (int*)carve((size_t)(N + 1) * 4);
  int*   parts   = (int*)carve(256 * 4);
  int*   ssrc    = (int*)carve((size_t)E * 4);
  float* snorm   = (float*)carve((size_t)E * 4);
  float* bufA    = (float*)carve((size_t)N * 128 * 4);
  float* bufB    = (float*)carve((size_t)N * 128 * 4);
  (void)ws_size; (void)n_in; (void)out_size;

  const int nThreads = 256;
  int gN  = (N + nThreads - 1) / nThreads;
  int gE  = (E + nThreads - 1) / nThreads;
  int nb  = (N + 1023) / 1024;               // scan blocks (98)

  // --- graph preprocessing (shared across the 3 layers) ---
  init_kernel<<<gN, nThreads, 0, stream>>>(dinv, counts, fillc, N);
  edge_deg_kernel<<<gE, nThreads, 0, stream>>>(ei, ew, dinv, counts, E);
  dinv_kernel<<<gN, nThreads, 0, stream>>>(dinv, N);
  scanA<<<nb, 1024, 0, stream>>>(counts, row_ptr, parts, N);
  scanB<<<1, 128, 0, stream>>>(parts, nb);
  scanC<<<nb, 1024, 0, stream>>>(row_ptr, parts, N);
  fill_kernel<<<gE, nThreads, 0, stream>>>(ei, ew, dinv, row_ptr, fillc, ssrc, snorm, E);

  const int gRows = (N + 255) / 256;         // 391 row-blocks
  int gAgg128 = (N * 32 + nThreads - 1) / nThreads;
  int gAgg64  = (N * 16 + nThreads - 1) / nThreads;

  // --- layer 1: xw1 = x@W1 -> bufA; aggregate+bias+relu -> bufB ---
  gemm_rows_kernel<64><<<dim3(gRows, 2), nThreads, 0, stream>>>(x, W1, bufA, N, 128);
  agg_kernel<128, true><<<gAgg128, nThreads, 0, stream>>>(bufA, row_ptr, ssrc, snorm, dinv, b1, bufB, N);

  // --- layer 2: xw2 = h1@W2 -> bufA; aggregate+bias+relu -> bufB ---
  gemm_rows_kernel<64><<<dim3(gRows, 2), nThreads, 0, stream>>>(bufB, W2, bufA, N, 128);
  agg_kernel<128, true><<<gAgg128, nThreads, 0, stream>>>(bufA, row_ptr, ssrc, snorm, dinv, b2, bufB, N);

  // --- layer 3: xw3 = h2@W3 -> bufA; aggregate+bias (no relu) -> d_out ---
  gemm_rows_kernel<64><<<dim3(gRows, 1), nThreads, 0, stream>>>(bufB, W3, bufA, N, 64);
  agg_kernel<64, false><<<gAgg64, nThreads, 0, stream>>>(bufA, row_ptr, ssrc, snorm, dinv, b3, (float*)d_out, N);
}

// Round 3
// 693.381 us; speedup vs baseline: 1.5023x; 1.1722x over previous
//
#include <hip/hip_runtime.h>
#include <math.h>

// ---------------------------------------------------------------------------
// GCN 3-layer forward on MI355X.
// Round 2 changes (edge_deg was atomic-op-bound: 140us, 32B HBM write/atomic):
//  - ONE packed 64-bit atomicAdd per edge: hi32=count, lo32=Q24 weight sum.
//  - init kernels replaced by hipMemsetAsync.
//  - CSR payload as int2{src, norm_bits}: 1x8B scattered write in fill,
//    1x8B broadcast load per edge in agg (was 2x4B each).
// ---------------------------------------------------------------------------

__global__ __launch_bounds__(256) void edge_pass_kernel(const int* __restrict__ ei,
    const float* __restrict__ ew, unsigned long long* __restrict__ packed, int E) {
  int e = blockIdx.x * 256 + threadIdx.x;
  if (e >= E) return;
  int d = ei[E + e];                       // dst row of edge_index
  unsigned wfix = (unsigned)__float2uint_rn(ew[e] * 16777216.0f);  // Q24
  unsigned long long inc = (1ULL << 32) | (unsigned long long)wfix;
  atomicAdd(&packed[d], inc);
}

__global__ __launch_bounds__(256) void dinv_kernel(const unsigned long long* __restrict__ packed,
    float* __restrict__ dinv, int n) {
  int i = blockIdx.x * 256 + threadIdx.x;
  if (i >= n) return;
  float deg = 1.0f + (float)(unsigned)(packed[i] & 0xffffffffULL) * (1.0f / 16777216.0f);
  dinv[i] = 1.0f / sqrtf(deg);             // deg >= 1 always (self-loop weight 1)
}

// ---- 3-kernel exclusive scan of counts (hi32 of packed) -> row_ptr ---------
__global__ __launch_bounds__(1024) void scanA(const unsigned long long* __restrict__ packed,
    int* __restrict__ row_ptr, int* __restrict__ partials, int n) {
  __shared__ int sd[1024];
  int t = threadIdx.x;
  int i = blockIdx.x * 1024 + t;
  int v = (i < n) ? (int)(packed[i] >> 32) : 0;
  sd[t] = v;
  __syncthreads();
  for (int off = 1; off < 1024; off <<= 1) {
    int u = (t >= off) ? sd[t - off] : 0;
    __syncthreads();
    sd[t] += u;
    __syncthreads();
  }
  int incl = sd[t];
  if (i < n) row_ptr[i] = incl - v;           // block-local exclusive
  if (t == 1023) partials[blockIdx.x] = incl; // block total
}

__global__ __launch_bounds__(128) void scanB(int* partials, int nb) {
  __shared__ int sd[128];
  int t = threadIdx.x;
  int v = (t < nb) ? partials[t] : 0;
  sd[t] = v;
  __syncthreads();
  for (int off = 1; off < 128; off <<= 1) {
    int u = (t >= off) ? sd[t - off] : 0;
    __syncthreads();
    sd[t] += u;
    __syncthreads();
  }
  int incl = sd[t];
  partials[t] = incl - v;                     // exclusive block offsets
  if (t == nb - 1) partials[255] = incl;      // grand total -> slot 255
}

__global__ __launch_bounds__(1024) void scanC(int* row_ptr, const int* __restrict__ partials, int n) {
  int i = blockIdx.x * 1024 + threadIdx.x;
  if (i < n) row_ptr[i] += partials[blockIdx.x];
  if (i == 0) row_ptr[n] = partials[255];
}

__global__ __launch_bounds__(256) void fill_kernel(const int* __restrict__ ei,
    const float* __restrict__ ew, const float* __restrict__ dinv,
    const int* __restrict__ row_ptr, int* __restrict__ fillc,
    int2* __restrict__ epair, int E) {
  int e = blockIdx.x * 256 + threadIdx.x;
  if (e >= E) return;
  int s = ei[e], d = ei[E + e];
  float nw = dinv[s] * ew[e] * dinv[d];
  int p = row_ptr[d] + atomicAdd(&fillc[d], 1);
  epair[p] = make_int2(s, __float_as_int(nw));
}

// ---- fp32 GEMM, row-per-thread: C[M,N] = A[M,128] @ W[128,N] ---------------
// Block = 256 threads = 256 rows; blockIdx.y selects a 64-column slice of W.
// W slice staged in 32KB LDS, read as wave-uniform broadcasts; A row streamed
// float4 from global (L3-resident); acc[64] in VGPRs.
template <int NCOL>
__global__ __launch_bounds__(256) void gemm_rows_kernel(const float* __restrict__ A,
    const float* __restrict__ W, float* __restrict__ C, int M, int N) {
  __shared__ float Ws[128][NCOL];
  const int col0 = blockIdx.y * NCOL;
  for (int i = threadIdx.x; i < 128 * NCOL / 4; i += 256) {
    int k = i / (NCOL / 4);
    int c4 = i % (NCOL / 4);
    *(float4*)&Ws[k][c4 * 4] = *(const float4*)&W[k * N + col0 + c4 * 4];
  }
  __syncthreads();
  int r = blockIdx.x * 256 + threadIdx.x;
  if (r >= M) return;
  const float4* a4 = (const float4*)(A + (size_t)r * 128);
  float acc[NCOL] = {};
  float4 a = a4[0];
#pragma unroll 1
  for (int k4 = 0; k4 < 32; k4++) {
    float4 cur = a;
    if (k4 < 31) a = a4[k4 + 1];            // prefetch next A chunk
    float av[4] = {cur.x, cur.y, cur.z, cur.w};
#pragma unroll
    for (int kk = 0; kk < 4; kk++) {
      const float* wrow = &Ws[k4 * 4 + kk][0];
#pragma unroll
      for (int c = 0; c < NCOL; c++)
        acc[c] = fmaf(av[kk], wrow[c], acc[c]);
    }
  }
  float* crow = C + (size_t)r * N + col0;
#pragma unroll
  for (int c = 0; c < NCOL; c += 4)
    *(float4*)&crow[c] = make_float4(acc[c], acc[c + 1], acc[c + 2], acc[c + 3]);
}

// ---- aggregation: out[n] = sum_{e: dst=n} norm_e * xw[src_e] + dinv^2*xw[n] + b
template <int F, bool RELU>
__global__ __launch_bounds__(256) void agg_kernel(const float* __restrict__ xw,
    const int* __restrict__ row_ptr, const int2* __restrict__ epair,
    const float* __restrict__ dinv, const float* __restrict__ bias,
    float* __restrict__ out, int Nn) {
  constexpr int LPN = F / 4;                  // lanes per node (float4 each)
  int t = blockIdx.x * 256 + threadIdx.x;
  int node = t / LPN;
  int lane = t % LPN;
  if (node >= Nn) return;
  const float4* xw4 = (const float4*)xw;
  int start = row_ptr[node];
  int end = row_ptr[node + 1];
  float ax = 0.f, ay = 0.f, az = 0.f, aw = 0.f;
  for (int p = start; p < end; ++p) {
    int2 pr = epair[p];                       // 8B broadcast across node group
    int s = pr.x;
    float nw = __int_as_float(pr.y);
    float4 v = xw4[(size_t)s * LPN + lane];
    ax = fmaf(nw, v.x, ax); ay = fmaf(nw, v.y, ay);
    az = fmaf(nw, v.z, az); aw = fmaf(nw, v.w, aw);
  }
  float di = dinv[node];
  float sw = di * di;
  float4 sv = xw4[(size_t)node * LPN + lane];
  ax = fmaf(sw, sv.x, ax); ay = fmaf(sw, sv.y, ay);
  az = fmaf(sw, sv.z, az); aw = fmaf(sw, sv.w, aw);
  float4 b = ((const float4*)bias)[lane];
  ax += b.x; ay += b.y; az += b.z; aw += b.w;
  if (RELU) {
    ax = fmaxf(ax, 0.f); ay = fmaxf(ay, 0.f);
    az = fmaxf(az, 0.f); aw = fmaxf(aw, 0.f);
  }
  ((float4*)out)[(size_t)node * LPN + lane] = make_float4(ax, ay, az, aw);
}

// ---------------------------------------------------------------------------
extern "C" void kernel_launch(void* const* d_in, const int* in_sizes, int n_in,
                              void* d_out, int out_size, void* d_ws, size_t ws_size,
                              hipStream_t stream) {
  const float* x  = (const float*)d_in[0];
  const int*   ei = (const int*)d_in[1];     // int32, [2,E] flat
  const float* ew = (const float*)d_in[2];
  const float* W1 = (const float*)d_in[3];
  const float* b1 = (const float*)d_in[4];
  const float* W2 = (const float*)d_in[5];
  const float* b2 = (const float*)d_in[6];
  const float* W3 = (const float*)d_in[7];
  const float* b3 = (const float*)d_in[8];

  const int N = in_sizes[0] / 128;           // 100000
  const int E = in_sizes[2];                 // 1600000

  // workspace carve (256B aligned)
  char* ws = (char*)d_ws;
  size_t off = 0;
  auto carve = [&](size_t bytes) -> void* {
    void* p = ws + off;
    off += (bytes + 255) & ~(size_t)255;
    return p;
  };
  unsigned long long* packed = (unsigned long long*)carve((size_t)N * 8);
  int*   fillc   = (int*)carve((size_t)N * 4);
  float* dinv    = (float*)carve((size_t)N * 4);
  int*   row_ptr = (int*)carve((size_t)(N + 1) * 4);
  int*   parts   = (int*)carve(256 * 4);
  int2*  epair   = (int2*)carve((size_t)E * 8);
  float* bufA    = (float*)carve((size_t)N * 128 * 4);
  float* bufB    = (float*)carve((size_t)N * 128 * 4);
  (void)ws_size; (void)n_in; (void)out_size;

  const int nThreads = 256;
  int gN  = (N + nThreads - 1) / nThreads;
  int gE  = (E + nThreads - 1) / nThreads;
  int nb  = (N + 1023) / 1024;               // scan blocks (98)

  // --- graph preprocessing (shared across the 3 layers) ---
  hipMemsetAsync(packed, 0, (size_t)N * 8, stream);
  hipMemsetAsync(fillc, 0, (size_t)N * 4, stream);
  edge_pass_kernel<<<gE, nThreads, 0, stream>>>(ei, ew, packed, E);
  dinv_kernel<<<gN, nThreads, 0, stream>>>(packed, dinv, N);
  scanA<<<nb, 1024, 0, stream>>>(packed, row_ptr, parts, N);
  scanB<<<1, 128, 0, stream>>>(parts, nb);
  scanC<<<nb, 1024, 0, stream>>>(row_ptr, parts, N);
  fill_kernel<<<gE, nThreads, 0, stream>>>(ei, ew, dinv, row_ptr, fillc, epair, E);

  const int gRows = (N + 255) / 256;         // 391 row-blocks
  int gAgg128 = (N * 32 + nThreads - 1) / nThreads;
  int gAgg64  = (N * 16 + nThreads - 1) / nThreads;

  // --- layer 1: xw1 = x@W1 -> bufA; aggregate+bias+relu -> bufB ---
  gemm_rows_kernel<64><<<dim3(gRows, 2), nThreads, 0, stream>>>(x, W1, bufA, N, 128);
  agg_kernel<128, true><<<gAgg128, nThreads, 0, stream>>>(bufA, row_ptr, epair, dinv, b1, bufB, N);

  // --- layer 2: xw2 = h1@W2 -> bufA; aggregate+bias+relu -> bufB ---
  gemm_rows_kernel<64><<<dim3(gRows, 2), nThreads, 0, stream>>>(bufB, W2, bufA, N, 128);
  agg_kernel<128, true><<<gAgg128, nThreads, 0, stream>>>(bufA, row_ptr, epair, dinv, b2, bufB, N);

  // --- layer 3: xw3 = h2@W3 -> bufA; aggregate+bias (no relu) -> d_out ---
  gemm_rows_kernel<64><<<dim3(gRows, 1), nThreads, 0, stream>>>(bufB, W3, bufA, N, 64);
  agg_kernel<64, false><<<gAgg64, nThreads, 0, stream>>>(bufA, row_ptr, epair, dinv, b3, (float*)d_out, N);
}

// Round 4
// 665.972 us; speedup vs baseline: 1.5641x; 1.0412x over previous
//
#include <hip/hip_runtime.h>
#include <math.h>

// ---------------------------------------------------------------------------
// GCN 3-layer forward on MI355X.
// Round 3 change: agg_kernel was latency-bound (127us, VALU 13%, fetch 46%,
// one dependent gather in flight per wave). Edge loop hand-unrolled x4:
// 4 epair loads -> 4 independent float4 gathers in flight -> 2 fma chains.
// ---------------------------------------------------------------------------

__global__ __launch_bounds__(256) void edge_pass_kernel(const int* __restrict__ ei,
    const float* __restrict__ ew, unsigned long long* __restrict__ packed, int E) {
  int e = blockIdx.x * 256 + threadIdx.x;
  if (e >= E) return;
  int d = ei[E + e];                       // dst row of edge_index
  unsigned wfix = (unsigned)__float2uint_rn(ew[e] * 16777216.0f);  // Q24
  unsigned long long inc = (1ULL << 32) | (unsigned long long)wfix;
  atomicAdd(&packed[d], inc);
}

__global__ __launch_bounds__(256) void dinv_kernel(const unsigned long long* __restrict__ packed,
    float* __restrict__ dinv, int n) {
  int i = blockIdx.x * 256 + threadIdx.x;
  if (i >= n) return;
  float deg = 1.0f + (float)(unsigned)(packed[i] & 0xffffffffULL) * (1.0f / 16777216.0f);
  dinv[i] = 1.0f / sqrtf(deg);             // deg >= 1 always (self-loop weight 1)
}

// ---- 3-kernel exclusive scan of counts (hi32 of packed) -> row_ptr ---------
__global__ __launch_bounds__(1024) void scanA(const unsigned long long* __restrict__ packed,
    int* __restrict__ row_ptr, int* __restrict__ partials, int n) {
  __shared__ int sd[1024];
  int t = threadIdx.x;
  int i = blockIdx.x * 1024 + t;
  int v = (i < n) ? (int)(packed[i] >> 32) : 0;
  sd[t] = v;
  __syncthreads();
  for (int off = 1; off < 1024; off <<= 1) {
    int u = (t >= off) ? sd[t - off] : 0;
    __syncthreads();
    sd[t] += u;
    __syncthreads();
  }
  int incl = sd[t];
  if (i < n) row_ptr[i] = incl - v;           // block-local exclusive
  if (t == 1023) partials[blockIdx.x] = incl; // block total
}

__global__ __launch_bounds__(128) void scanB(int* partials, int nb) {
  __shared__ int sd[128];
  int t = threadIdx.x;
  int v = (t < nb) ? partials[t] : 0;
  sd[t] = v;
  __syncthreads();
  for (int off = 1; off < 128; off <<= 1) {
    int u = (t >= off) ? sd[t - off] : 0;
    __syncthreads();
    sd[t] += u;
    __syncthreads();
  }
  int incl = sd[t];
  partials[t] = incl - v;                     // exclusive block offsets
  if (t == nb - 1) partials[255] = incl;      // grand total -> slot 255
}

__global__ __launch_bounds__(1024) void scanC(int* row_ptr, const int* __restrict__ partials, int n) {
  int i = blockIdx.x * 1024 + threadIdx.x;
  if (i < n) row_ptr[i] += partials[blockIdx.x];
  if (i == 0) row_ptr[n] = partials[255];
}

__global__ __launch_bounds__(256) void fill_kernel(const int* __restrict__ ei,
    const float* __restrict__ ew, const float* __restrict__ dinv,
    const int* __restrict__ row_ptr, int* __restrict__ fillc,
    int2* __restrict__ epair, int E) {
  int e = blockIdx.x * 256 + threadIdx.x;
  if (e >= E) return;
  int s = ei[e], d = ei[E + e];
  float nw = dinv[s] * ew[e] * dinv[d];
  int p = row_ptr[d] + atomicAdd(&fillc[d], 1);
  epair[p] = make_int2(s, __float_as_int(nw));
}

// ---- fp32 GEMM, row-per-thread: C[M,N] = A[M,128] @ W[128,N] ---------------
// Block = 256 threads = 256 rows; blockIdx.y selects a 64-column slice of W.
// W slice staged in 32KB LDS, read as wave-uniform broadcasts; A row streamed
// float4 from global (L3-resident); acc[64] in VGPRs.
template <int NCOL>
__global__ __launch_bounds__(256) void gemm_rows_kernel(const float* __restrict__ A,
    const float* __restrict__ W, float* __restrict__ C, int M, int N) {
  __shared__ float Ws[128][NCOL];
  const int col0 = blockIdx.y * NCOL;
  for (int i = threadIdx.x; i < 128 * NCOL / 4; i += 256) {
    int k = i / (NCOL / 4);
    int c4 = i % (NCOL / 4);
    *(float4*)&Ws[k][c4 * 4] = *(const float4*)&W[k * N + col0 + c4 * 4];
  }
  __syncthreads();
  int r = blockIdx.x * 256 + threadIdx.x;
  if (r >= M) return;
  const float4* a4 = (const float4*)(A + (size_t)r * 128);
  float acc[NCOL] = {};
  float4 a = a4[0];
#pragma unroll 1
  for (int k4 = 0; k4 < 32; k4++) {
    float4 cur = a;
    if (k4 < 31) a = a4[k4 + 1];            // prefetch next A chunk
    float av[4] = {cur.x, cur.y, cur.z, cur.w};
#pragma unroll
    for (int kk = 0; kk < 4; kk++) {
      const float* wrow = &Ws[k4 * 4 + kk][0];
#pragma unroll
      for (int c = 0; c < NCOL; c++)
        acc[c] = fmaf(av[kk], wrow[c], acc[c]);
    }
  }
  float* crow = C + (size_t)r * N + col0;
#pragma unroll
  for (int c = 0; c < NCOL; c += 4)
    *(float4*)&crow[c] = make_float4(acc[c], acc[c + 1], acc[c + 2], acc[c + 3]);
}

// ---- aggregation: out[n] = sum_{e: dst=n} norm_e * xw[src_e] + dinv^2*xw[n] + b
// x4 unrolled edge loop: 4 independent gathers in flight per node-group.
template <int F, bool RELU>
__global__ __launch_bounds__(256) void agg_kernel(const float* __restrict__ xw,
    const int* __restrict__ row_ptr, const int2* __restrict__ epair,
    const float* __restrict__ dinv, const float* __restrict__ bias,
    float* __restrict__ out, int Nn) {
  constexpr int LPN = F / 4;                  // lanes per node (float4 each)
  int t = blockIdx.x * 256 + threadIdx.x;
  int node = t / LPN;
  int lane = t % LPN;
  if (node >= Nn) return;
  const float4* xw4 = (const float4*)xw;
  int start = row_ptr[node];
  int end = row_ptr[node + 1];
  float a0x = 0.f, a0y = 0.f, a0z = 0.f, a0w = 0.f;   // chain 0
  float a1x = 0.f, a1y = 0.f, a1z = 0.f, a1w = 0.f;   // chain 1
  int p = start;
  for (; p + 4 <= end; p += 4) {
    int2 e0 = epair[p];
    int2 e1 = epair[p + 1];
    int2 e2 = epair[p + 2];
    int2 e3 = epair[p + 3];
    float4 v0 = xw4[(size_t)e0.x * LPN + lane];
    float4 v1 = xw4[(size_t)e1.x * LPN + lane];
    float4 v2 = xw4[(size_t)e2.x * LPN + lane];
    float4 v3 = xw4[(size_t)e3.x * LPN + lane];
    float n0 = __int_as_float(e0.y), n1 = __int_as_float(e1.y);
    float n2 = __int_as_float(e2.y), n3 = __int_as_float(e3.y);
    a0x = fmaf(n0, v0.x, a0x); a0y = fmaf(n0, v0.y, a0y);
    a0z = fmaf(n0, v0.z, a0z); a0w = fmaf(n0, v0.w, a0w);
    a1x = fmaf(n1, v1.x, a1x); a1y = fmaf(n1, v1.y, a1y);
    a1z = fmaf(n1, v1.z, a1z); a1w = fmaf(n1, v1.w, a1w);
    a0x = fmaf(n2, v2.x, a0x); a0y = fmaf(n2, v2.y, a0y);
    a0z = fmaf(n2, v2.z, a0z); a0w = fmaf(n2, v2.w, a0w);
    a1x = fmaf(n3, v3.x, a1x); a1y = fmaf(n3, v3.y, a1y);
    a1z = fmaf(n3, v3.z, a1z); a1w = fmaf(n3, v3.w, a1w);
  }
  for (; p < end; ++p) {
    int2 pr = epair[p];
    float nw = __int_as_float(pr.y);
    float4 v = xw4[(size_t)pr.x * LPN + lane];
    a0x = fmaf(nw, v.x, a0x); a0y = fmaf(nw, v.y, a0y);
    a0z = fmaf(nw, v.z, a0z); a0w = fmaf(nw, v.w, a0w);
  }
  float di = dinv[node];
  float sw = di * di;
  float4 sv = xw4[(size_t)node * LPN + lane];
  a0x = fmaf(sw, sv.x, a0x); a0y = fmaf(sw, sv.y, a0y);
  a0z = fmaf(sw, sv.z, a0z); a0w = fmaf(sw, sv.w, a0w);
  float4 b = ((const float4*)bias)[lane];
  float ox = a0x + a1x + b.x;
  float oy = a0y + a1y + b.y;
  float oz = a0z + a1z + b.z;
  float ow = a0w + a1w + b.w;
  if (RELU) {
    ox = fmaxf(ox, 0.f); oy = fmaxf(oy, 0.f);
    oz = fmaxf(oz, 0.f); ow = fmaxf(ow, 0.f);
  }
  ((float4*)out)[(size_t)node * LPN + lane] = make_float4(ox, oy, oz, ow);
}

// ---------------------------------------------------------------------------
extern "C" void kernel_launch(void* const* d_in, const int* in_sizes, int n_in,
                              void* d_out, int out_size, void* d_ws, size_t ws_size,
                              hipStream_t stream) {
  const float* x  = (const float*)d_in[0];
  const int*   ei = (const int*)d_in[1];     // int32, [2,E] flat
  const float* ew = (const float*)d_in[2];
  const float* W1 = (const float*)d_in[3];
  const float* b1 = (const float*)d_in[4];
  const float* W2 = (const float*)d_in[5];
  const float* b2 = (const float*)d_in[6];
  const float* W3 = (const float*)d_in[7];
  const float* b3 = (const float*)d_in[8];

  const int N = in_sizes[0] / 128;           // 100000
  const int E = in_sizes[2];                 // 1600000

  // workspace carve (256B aligned)
  char* ws = (char*)d_ws;
  size_t off = 0;
  auto carve = [&](size_t bytes) -> void* {
    void* p = ws + off;
    off += (bytes + 255) & ~(size_t)255;
    return p;
  };
  unsigned long long* packed = (unsigned long long*)carve((size_t)N * 8);
  int*   fillc   = (int*)carve((size_t)N * 4);
  float* dinv    = (float*)carve((size_t)N * 4);
  int*   row_ptr = (int*)carve((size_t)(N + 1) * 4);
  int*   parts   = (int*)carve(256 * 4);
  int2*  epair   = (int2*)carve((size_t)E * 8);
  float* bufA    = (float*)carve((size_t)N * 128 * 4);
  float* bufB    = (float*)carve((size_t)N * 128 * 4);
  (void)ws_size; (void)n_in; (void)out_size;

  const int nThreads = 256;
  int gN  = (N + nThreads - 1) / nThreads;
  int gE  = (E + nThreads - 1) / nThreads;
  int nb  = (N + 1023) / 1024;               // scan blocks (98)

  // --- graph preprocessing (shared across the 3 layers) ---
  hipMemsetAsync(packed, 0, (size_t)N * 8, stream);
  hipMemsetAsync(fillc, 0, (size_t)N * 4, stream);
  edge_pass_kernel<<<gE, nThreads, 0, stream>>>(ei, ew, packed, E);
  dinv_kernel<<<gN, nThreads, 0, stream>>>(packed, dinv, N);
  scanA<<<nb, 1024, 0, stream>>>(packed, row_ptr, parts, N);
  scanB<<<1, 128, 0, stream>>>(parts, nb);
  scanC<<<nb, 1024, 0, stream>>>(row_ptr, parts, N);
  fill_kernel<<<gE, nThreads, 0, stream>>>(ei, ew, dinv, row_ptr, fillc, epair, E);

  const int gRows = (N + 255) / 256;         // 391 row-blocks
  int gAgg128 = (N * 32 + nThreads - 1) / nThreads;
  int gAgg64  = (N * 16 + nThreads - 1) / nThreads;

  // --- layer 1: xw1 = x@W1 -> bufA; aggregate+bias+relu -> bufB ---
  gemm_rows_kernel<64><<<dim3(gRows, 2), nThreads, 0, stream>>>(x, W1, bufA, N, 128);
  agg_kernel<128, true><<<gAgg128, nThreads, 0, stream>>>(bufA, row_ptr, epair, dinv, b1, bufB, N);

  // --- layer 2: xw2 = h1@W2 -> bufA; aggregate+bias+relu -> bufB ---
  gemm_rows_kernel<64><<<dim3(gRows, 2), nThreads, 0, stream>>>(bufB, W2, bufA, N, 128);
  agg_kernel<128, true><<<gAgg128, nThreads, 0, stream>>>(bufA, row_ptr, epair, dinv, b2, bufB, N);

  // --- layer 3: xw3 = h2@W3 -> bufA; aggregate+bias (no relu) -> d_out ---
  gemm_rows_kernel<64><<<dim3(gRows, 1), nThreads, 0, stream>>>(bufB, W3, bufA, N, 64);
  agg_kernel<64, false><<<gAgg64, nThreads, 0, stream>>>(bufA, row_ptr, epair, dinv, b3, (float*)d_out, N);
}

// Round 5
// 579.158 us; speedup vs baseline: 1.7986x; 1.1499x over previous
//
#include <hip/hip_runtime.h>
#include <hip/hip_fp16.h>
#include <math.h>

// ---------------------------------------------------------------------------
// GCN 3-layer forward on MI355X.
// Round 4 change: agg is L2-fill-BW bound (406MB fetch @ ~3.8TB/s, unroll had
// no effect). Halve gathered bytes: GEMM writes an fp16 copy of xw; agg
// gathers fp16 rows (256B/edge), converts to fp32 for FMA. Self-loop term
// stays fp32. fp16 (not bf16): 2^-11 rel err keeps absmax ~1e-4 added.
// ---------------------------------------------------------------------------

__global__ __launch_bounds__(256) void edge_pass_kernel(const int* __restrict__ ei,
    const float* __restrict__ ew, unsigned long long* __restrict__ packed, int E) {
  int e = blockIdx.x * 256 + threadIdx.x;
  if (e >= E) return;
  int d = ei[E + e];                       // dst row of edge_index
  unsigned wfix = (unsigned)__float2uint_rn(ew[e] * 16777216.0f);  // Q24
  unsigned long long inc = (1ULL << 32) | (unsigned long long)wfix;
  atomicAdd(&packed[d], inc);
}

__global__ __launch_bounds__(256) void dinv_kernel(const unsigned long long* __restrict__ packed,
    float* __restrict__ dinv, int n) {
  int i = blockIdx.x * 256 + threadIdx.x;
  if (i >= n) return;
  float deg = 1.0f + (float)(unsigned)(packed[i] & 0xffffffffULL) * (1.0f / 16777216.0f);
  dinv[i] = 1.0f / sqrtf(deg);             // deg >= 1 always (self-loop weight 1)
}

// ---- 3-kernel exclusive scan of counts (hi32 of packed) -> row_ptr ---------
__global__ __launch_bounds__(1024) void scanA(const unsigned long long* __restrict__ packed,
    int* __restrict__ row_ptr, int* __restrict__ partials, int n) {
  __shared__ int sd[1024];
  int t = threadIdx.x;
  int i = blockIdx.x * 1024 + t;
  int v = (i < n) ? (int)(packed[i] >> 32) : 0;
  sd[t] = v;
  __syncthreads();
  for (int off = 1; off < 1024; off <<= 1) {
    int u = (t >= off) ? sd[t - off] : 0;
    __syncthreads();
    sd[t] += u;
    __syncthreads();
  }
  int incl = sd[t];
  if (i < n) row_ptr[i] = incl - v;           // block-local exclusive
  if (t == 1023) partials[blockIdx.x] = incl; // block total
}

__global__ __launch_bounds__(128) void scanB(int* partials, int nb) {
  __shared__ int sd[128];
  int t = threadIdx.x;
  int v = (t < nb) ? partials[t] : 0;
  sd[t] = v;
  __syncthreads();
  for (int off = 1; off < 128; off <<= 1) {
    int u = (t >= off) ? sd[t - off] : 0;
    __syncthreads();
    sd[t] += u;
    __syncthreads();
  }
  int incl = sd[t];
  partials[t] = incl - v;                     // exclusive block offsets
  if (t == nb - 1) partials[255] = incl;      // grand total -> slot 255
}

__global__ __launch_bounds__(1024) void scanC(int* row_ptr, const int* __restrict__ partials, int n) {
  int i = blockIdx.x * 1024 + threadIdx.x;
  if (i < n) row_ptr[i] += partials[blockIdx.x];
  if (i == 0) row_ptr[n] = partials[255];
}

__global__ __launch_bounds__(256) void fill_kernel(const int* __restrict__ ei,
    const float* __restrict__ ew, const float* __restrict__ dinv,
    const int* __restrict__ row_ptr, int* __restrict__ fillc,
    int2* __restrict__ epair, int E) {
  int e = blockIdx.x * 256 + threadIdx.x;
  if (e >= E) return;
  int s = ei[e], d = ei[E + e];
  float nw = dinv[s] * ew[e] * dinv[d];
  int p = row_ptr[d] + atomicAdd(&fillc[d], 1);
  epair[p] = make_int2(s, __float_as_int(nw));
}

__device__ __forceinline__ unsigned pkh2(float a, float b) {
  __half2 h = __float22half2_rn(make_float2(a, b));
  return *reinterpret_cast<unsigned*>(&h);
}

// ---- fp32 GEMM, row-per-thread: C[M,N] = A[M,128] @ W[128,N] ---------------
// Writes fp32 C (for self-loop path) and fp16 copy Ch (gather payload).
template <int NCOL>
__global__ __launch_bounds__(256) void gemm_rows_kernel(const float* __restrict__ A,
    const float* __restrict__ W, float* __restrict__ C,
    unsigned short* __restrict__ Ch, int M, int N) {
  __shared__ float Ws[128][NCOL];
  const int col0 = blockIdx.y * NCOL;
  for (int i = threadIdx.x; i < 128 * NCOL / 4; i += 256) {
    int k = i / (NCOL / 4);
    int c4 = i % (NCOL / 4);
    *(float4*)&Ws[k][c4 * 4] = *(const float4*)&W[k * N + col0 + c4 * 4];
  }
  __syncthreads();
  int r = blockIdx.x * 256 + threadIdx.x;
  if (r >= M) return;
  const float4* a4 = (const float4*)(A + (size_t)r * 128);
  float acc[NCOL] = {};
  float4 a = a4[0];
#pragma unroll 1
  for (int k4 = 0; k4 < 32; k4++) {
    float4 cur = a;
    if (k4 < 31) a = a4[k4 + 1];            // prefetch next A chunk
    float av[4] = {cur.x, cur.y, cur.z, cur.w};
#pragma unroll
    for (int kk = 0; kk < 4; kk++) {
      const float* wrow = &Ws[k4 * 4 + kk][0];
#pragma unroll
      for (int c = 0; c < NCOL; c++)
        acc[c] = fmaf(av[kk], wrow[c], acc[c]);
    }
  }
  float* crow = C + (size_t)r * N + col0;
#pragma unroll
  for (int c = 0; c < NCOL; c += 4)
    *(float4*)&crow[c] = make_float4(acc[c], acc[c + 1], acc[c + 2], acc[c + 3]);
  unsigned short* hrow = Ch + (size_t)r * N + col0;
#pragma unroll
  for (int c = 0; c < NCOL; c += 8) {
    uint4 pk;
    pk.x = pkh2(acc[c], acc[c + 1]);
    pk.y = pkh2(acc[c + 2], acc[c + 3]);
    pk.z = pkh2(acc[c + 4], acc[c + 5]);
    pk.w = pkh2(acc[c + 6], acc[c + 7]);
    *(uint4*)&hrow[c] = pk;
  }
}

// ---- aggregation: out[n] = sum_{e: dst=n} norm_e * xw_h[src_e] + dinv^2*xw[n] + b
// Gathers fp16 rows (8B/lane); self-loop from fp32 xw; x4 unrolled edge loop.
template <int F, bool RELU>
__global__ __launch_bounds__(256) void agg_kernel(const float* __restrict__ xwf,
    const unsigned short* __restrict__ xwh,
    const int* __restrict__ row_ptr, const int2* __restrict__ epair,
    const float* __restrict__ dinv, const float* __restrict__ bias,
    float* __restrict__ out, int Nn) {
  constexpr int LPN = F / 4;                  // lanes per node (4 dims each)
  int t = blockIdx.x * 256 + threadIdx.x;
  int node = t / LPN;
  int lane = t % LPN;
  if (node >= Nn) return;
  const uint2* xh = (const uint2*)xwh;        // 4 halves per uint2
  int start = row_ptr[node];
  int end = row_ptr[node + 1];
  float a0x = 0.f, a0y = 0.f, a0z = 0.f, a0w = 0.f;   // chain 0
  float a1x = 0.f, a1y = 0.f, a1z = 0.f, a1w = 0.f;   // chain 1
  int p = start;
  for (; p + 4 <= end; p += 4) {
    int2 e0 = epair[p];
    int2 e1 = epair[p + 1];
    int2 e2 = epair[p + 2];
    int2 e3 = epair[p + 3];
    uint2 u0 = xh[(size_t)e0.x * LPN + lane];
    uint2 u1 = xh[(size_t)e1.x * LPN + lane];
    uint2 u2 = xh[(size_t)e2.x * LPN + lane];
    uint2 u3 = xh[(size_t)e3.x * LPN + lane];
    float n0 = __int_as_float(e0.y), n1 = __int_as_float(e1.y);
    float n2 = __int_as_float(e2.y), n3 = __int_as_float(e3.y);
    float2 f0a = __half22float2(*(__half2*)&u0.x), f0b = __half22float2(*(__half2*)&u0.y);
    float2 f1a = __half22float2(*(__half2*)&u1.x), f1b = __half22float2(*(__half2*)&u1.y);
    float2 f2a = __half22float2(*(__half2*)&u2.x), f2b = __half22float2(*(__half2*)&u2.y);
    float2 f3a = __half22float2(*(__half2*)&u3.x), f3b = __half22float2(*(__half2*)&u3.y);
    a0x = fmaf(n0, f0a.x, a0x); a0y = fmaf(n0, f0a.y, a0y);
    a0z = fmaf(n0, f0b.x, a0z); a0w = fmaf(n0, f0b.y, a0w);
    a1x = fmaf(n1, f1a.x, a1x); a1y = fmaf(n1, f1a.y, a1y);
    a1z = fmaf(n1, f1b.x, a1z); a1w = fmaf(n1, f1b.y, a1w);
    a0x = fmaf(n2, f2a.x, a0x); a0y = fmaf(n2, f2a.y, a0y);
    a0z = fmaf(n2, f2b.x, a0z); a0w = fmaf(n2, f2b.y, a0w);
    a1x = fmaf(n3, f3a.x, a1x); a1y = fmaf(n3, f3a.y, a1y);
    a1z = fmaf(n3, f3b.x, a1z); a1w = fmaf(n3, f3b.y, a1w);
  }
  for (; p < end; ++p) {
    int2 pr = epair[p];
    float nw = __int_as_float(pr.y);
    uint2 u = xh[(size_t)pr.x * LPN + lane];
    float2 fa = __half22float2(*(__half2*)&u.x), fb = __half22float2(*(__half2*)&u.y);
    a0x = fmaf(nw, fa.x, a0x); a0y = fmaf(nw, fa.y, a0y);
    a0z = fmaf(nw, fb.x, a0z); a0w = fmaf(nw, fb.y, a0w);
  }
  float di = dinv[node];
  float sw = di * di;
  float4 sv = ((const float4*)xwf)[(size_t)node * LPN + lane];  // fp32 self row
  a0x = fmaf(sw, sv.x, a0x); a0y = fmaf(sw, sv.y, a0y);
  a0z = fmaf(sw, sv.z, a0z); a0w = fmaf(sw, sv.w, a0w);
  float4 b = ((const float4*)bias)[lane];
  float ox = a0x + a1x + b.x;
  float oy = a0y + a1y + b.y;
  float oz = a0z + a1z + b.z;
  float ow = a0w + a1w + b.w;
  if (RELU) {
    ox = fmaxf(ox, 0.f); oy = fmaxf(oy, 0.f);
    oz = fmaxf(oz, 0.f); ow = fmaxf(ow, 0.f);
  }
  ((float4*)out)[(size_t)node * LPN + lane] = make_float4(ox, oy, oz, ow);
}

// ---------------------------------------------------------------------------
extern "C" void kernel_launch(void* const* d_in, const int* in_sizes, int n_in,
                              void* d_out, int out_size, void* d_ws, size_t ws_size,
                              hipStream_t stream) {
  const float* x  = (const float*)d_in[0];
  const int*   ei = (const int*)d_in[1];     // int32, [2,E] flat
  const float* ew = (const float*)d_in[2];
  const float* W1 = (const float*)d_in[3];
  const float* b1 = (const float*)d_in[4];
  const float* W2 = (const float*)d_in[5];
  const float* b2 = (const float*)d_in[6];
  const float* W3 = (const float*)d_in[7];
  const float* b3 = (const float*)d_in[8];

  const int N = in_sizes[0] / 128;           // 100000
  const int E = in_sizes[2];                 // 1600000

  // workspace carve (256B aligned)
  char* ws = (char*)d_ws;
  size_t off = 0;
  auto carve = [&](size_t bytes) -> void* {
    void* p = ws + off;
    off += (bytes + 255) & ~(size_t)255;
    return p;
  };
  unsigned long long* packed = (unsigned long long*)carve((size_t)N * 8);
  int*   fillc   = (int*)carve((size_t)N * 4);
  float* dinv    = (float*)carve((size_t)N * 4);
  int*   row_ptr = (int*)carve((size_t)(N + 1) * 4);
  int*   parts   = (int*)carve(256 * 4);
  int2*  epair   = (int2*)carve((size_t)E * 8);
  float* bufA    = (float*)carve((size_t)N * 128 * 4);           // fp32 xw
  float* bufB    = (float*)carve((size_t)N * 128 * 4);           // fp32 h
  unsigned short* bufH = (unsigned short*)carve((size_t)N * 128 * 2);  // fp16 xw
  (void)ws_size; (void)n_in; (void)out_size;

  const int nThreads = 256;
  int gN  = (N + nThreads - 1) / nThreads;
  int gE  = (E + nThreads - 1) / nThreads;
  int nb  = (N + 1023) / 1024;               // scan blocks (98)

  // --- graph preprocessing (shared across the 3 layers) ---
  hipMemsetAsync(packed, 0, (size_t)N * 8, stream);
  hipMemsetAsync(fillc, 0, (size_t)N * 4, stream);
  edge_pass_kernel<<<gE, nThreads, 0, stream>>>(ei, ew, packed, E);
  dinv_kernel<<<gN, nThreads, 0, stream>>>(packed, dinv, N);
  scanA<<<nb, 1024, 0, stream>>>(packed, row_ptr, parts, N);
  scanB<<<1, 128, 0, stream>>>(parts, nb);
  scanC<<<nb, 1024, 0, stream>>>(row_ptr, parts, N);
  fill_kernel<<<gE, nThreads, 0, stream>>>(ei, ew, dinv, row_ptr, fillc, epair, E);

  const int gRows = (N + 255) / 256;         // 391 row-blocks
  int gAgg128 = (N * 32 + nThreads - 1) / nThreads;
  int gAgg64  = (N * 16 + nThreads - 1) / nThreads;

  // --- layer 1: xw1 = x@W1 -> bufA(+fp16 bufH); aggregate+bias+relu -> bufB
  gemm_rows_kernel<64><<<dim3(gRows, 2), nThreads, 0, stream>>>(x, W1, bufA, bufH, N, 128);
  agg_kernel<128, true><<<gAgg128, nThreads, 0, stream>>>(bufA, bufH, row_ptr, epair, dinv, b1, bufB, N);

  // --- layer 2 ---
  gemm_rows_kernel<64><<<dim3(gRows, 2), nThreads, 0, stream>>>(bufB, W2, bufA, bufH, N, 128);
  agg_kernel<128, true><<<gAgg128, nThreads, 0, stream>>>(bufA, bufH, row_ptr, epair, dinv, b2, bufB, N);

  // --- layer 3 (64-wide, no relu) -> d_out ---
  gemm_rows_kernel<64><<<dim3(gRows, 1), nThreads, 0, stream>>>(bufB, W3, bufA, bufH, N, 64);
  agg_kernel<64, false><<<gAgg64, nThreads, 0, stream>>>(bufA, bufH, row_ptr, epair, dinv, b3, (float*)d_out, N);
}

// Round 6
// 513.215 us; speedup vs baseline: 2.0297x; 1.1285x over previous
//
#include <hip/hip_runtime.h>
#include <hip/hip_fp16.h>
#include <math.h>

// ---------------------------------------------------------------------------
// GCN 3-layer forward on MI355X.
// Round 5 changes (gemm was top: 175MB traffic @1.75TB/s, VALU 23%, occ 23%):
//  - xw kept ONLY in fp16 (gemm writes 25MB not 75MB; agg self-term reads fp16)
//  - gemm blocks 256->128 threads (grid 1564: ~6 blocks/CU vs 3)
//  - 4-deep A prefetch (K in 8 chunks of 16, next chunk loads in flight)
// ---------------------------------------------------------------------------

__global__ __launch_bounds__(256) void edge_pass_kernel(const int* __restrict__ ei,
    const float* __restrict__ ew, unsigned long long* __restrict__ packed, int E) {
  int e = blockIdx.x * 256 + threadIdx.x;
  if (e >= E) return;
  int d = ei[E + e];                       // dst row of edge_index
  unsigned wfix = (unsigned)__float2uint_rn(ew[e] * 16777216.0f);  // Q24
  unsigned long long inc = (1ULL << 32) | (unsigned long long)wfix;
  atomicAdd(&packed[d], inc);
}

__global__ __launch_bounds__(256) void dinv_kernel(const unsigned long long* __restrict__ packed,
    float* __restrict__ dinv, int n) {
  int i = blockIdx.x * 256 + threadIdx.x;
  if (i >= n) return;
  float deg = 1.0f + (float)(unsigned)(packed[i] & 0xffffffffULL) * (1.0f / 16777216.0f);
  dinv[i] = 1.0f / sqrtf(deg);             // deg >= 1 always (self-loop weight 1)
}

// ---- 3-kernel exclusive scan of counts (hi32 of packed) -> row_ptr ---------
__global__ __launch_bounds__(1024) void scanA(const unsigned long long* __restrict__ packed,
    int* __restrict__ row_ptr, int* __restrict__ partials, int n) {
  __shared__ int sd[1024];
  int t = threadIdx.x;
  int i = blockIdx.x * 1024 + t;
  int v = (i < n) ? (int)(packed[i] >> 32) : 0;
  sd[t] = v;
  __syncthreads();
  for (int off = 1; off < 1024; off <<= 1) {
    int u = (t >= off) ? sd[t - off] : 0;
    __syncthreads();
    sd[t] += u;
    __syncthreads();
  }
  int incl = sd[t];
  if (i < n) row_ptr[i] = incl - v;           // block-local exclusive
  if (t == 1023) partials[blockIdx.x] = incl; // block total
}

__global__ __launch_bounds__(128) void scanB(int* partials, int nb) {
  __shared__ int sd[128];
  int t = threadIdx.x;
  int v = (t < nb) ? partials[t] : 0;
  sd[t] = v;
  __syncthreads();
  for (int off = 1; off < 128; off <<= 1) {
    int u = (t >= off) ? sd[t - off] : 0;
    __syncthreads();
    sd[t] += u;
    __syncthreads();
  }
  int incl = sd[t];
  partials[t] = incl - v;                     // exclusive block offsets
  if (t == nb - 1) partials[255] = incl;      // grand total -> slot 255
}

__global__ __launch_bounds__(1024) void scanC(int* row_ptr, const int* __restrict__ partials, int n) {
  int i = blockIdx.x * 1024 + threadIdx.x;
  if (i < n) row_ptr[i] += partials[blockIdx.x];
  if (i == 0) row_ptr[n] = partials[255];
}

__global__ __launch_bounds__(256) void fill_kernel(const int* __restrict__ ei,
    const float* __restrict__ ew, const float* __restrict__ dinv,
    const int* __restrict__ row_ptr, int* __restrict__ fillc,
    int2* __restrict__ epair, int E) {
  int e = blockIdx.x * 256 + threadIdx.x;
  if (e >= E) return;
  int s = ei[e], d = ei[E + e];
  float nw = dinv[s] * ew[e] * dinv[d];
  int p = row_ptr[d] + atomicAdd(&fillc[d], 1);
  epair[p] = make_int2(s, __float_as_int(nw));
}

__device__ __forceinline__ unsigned pkh2(float a, float b) {
  __half2 h = __float22half2_rn(make_float2(a, b));
  return *reinterpret_cast<unsigned*>(&h);
}

// ---- fp32 GEMM, row-per-thread: Ch[M,N] = fp16(A[M,128] @ W[128,N]) --------
// 128-thread blocks; blockIdx.y = 64-col slice. W slice in 32KB LDS read as
// wave-uniform broadcasts. A row consumed in 8 chunks of 16 floats with the
// next chunk's 4 float4 loads in flight during compute.
template <int NCOL>
__global__ __launch_bounds__(128) void gemm_rows_kernel(const float* __restrict__ A,
    const float* __restrict__ W, unsigned short* __restrict__ Ch, int M, int N) {
  __shared__ float Ws[128][NCOL];
  const int col0 = blockIdx.y * NCOL;
  for (int i = threadIdx.x; i < 128 * NCOL / 4; i += 128) {
    int k = i / (NCOL / 4);
    int c4 = i % (NCOL / 4);
    *(float4*)&Ws[k][c4 * 4] = *(const float4*)&W[k * N + col0 + c4 * 4];
  }
  __syncthreads();
  int r = blockIdx.x * 128 + threadIdx.x;
  if (r >= M) return;
  const float4* a4 = (const float4*)(A + (size_t)r * 128);
  float4 cur[4];
#pragma unroll
  for (int i = 0; i < 4; i++) cur[i] = a4[i];
  float acc[NCOL] = {};
#pragma unroll 1
  for (int ch = 0; ch < 8; ch++) {
    float4 nxt[4];
    int nidx = (ch < 7) ? (ch + 1) * 4 : 28;   // last iter: harmless L1-hot reload
#pragma unroll
    for (int i = 0; i < 4; i++) nxt[i] = a4[nidx + i];
#pragma unroll
    for (int i = 0; i < 4; i++) {
      float av[4] = {cur[i].x, cur[i].y, cur[i].z, cur[i].w};
#pragma unroll
      for (int kk = 0; kk < 4; kk++) {
        const float* wrow = &Ws[ch * 16 + i * 4 + kk][0];
#pragma unroll
        for (int c = 0; c < NCOL; c++)
          acc[c] = fmaf(av[kk], wrow[c], acc[c]);
      }
    }
#pragma unroll
    for (int i = 0; i < 4; i++) cur[i] = nxt[i];
  }
  unsigned short* hrow = Ch + (size_t)r * N + col0;
#pragma unroll
  for (int c = 0; c < NCOL; c += 8) {
    uint4 pk;
    pk.x = pkh2(acc[c], acc[c + 1]);
    pk.y = pkh2(acc[c + 2], acc[c + 3]);
    pk.z = pkh2(acc[c + 4], acc[c + 5]);
    pk.w = pkh2(acc[c + 6], acc[c + 7]);
    *(uint4*)&hrow[c] = pk;
  }
}

// ---- aggregation: out[n] = sum_{e: dst=n} norm_e * xw[src_e] + dinv^2*xw[n] + b
// All xw reads fp16 (gather 8B/lane, x4 unrolled; self-row also fp16).
template <int F, bool RELU>
__global__ __launch_bounds__(256) void agg_kernel(const unsigned short* __restrict__ xwh,
    const int* __restrict__ row_ptr, const int2* __restrict__ epair,
    const float* __restrict__ dinv, const float* __restrict__ bias,
    float* __restrict__ out, int Nn) {
  constexpr int LPN = F / 4;                  // lanes per node (4 dims each)
  int t = blockIdx.x * 256 + threadIdx.x;
  int node = t / LPN;
  int lane = t % LPN;
  if (node >= Nn) return;
  const uint2* xh = (const uint2*)xwh;        // 4 halves per uint2
  int start = row_ptr[node];
  int end = row_ptr[node + 1];
  float a0x = 0.f, a0y = 0.f, a0z = 0.f, a0w = 0.f;   // chain 0
  float a1x = 0.f, a1y = 0.f, a1z = 0.f, a1w = 0.f;   // chain 1
  int p = start;
  for (; p + 4 <= end; p += 4) {
    int2 e0 = epair[p];
    int2 e1 = epair[p + 1];
    int2 e2 = epair[p + 2];
    int2 e3 = epair[p + 3];
    uint2 u0 = xh[(size_t)e0.x * LPN + lane];
    uint2 u1 = xh[(size_t)e1.x * LPN + lane];
    uint2 u2 = xh[(size_t)e2.x * LPN + lane];
    uint2 u3 = xh[(size_t)e3.x * LPN + lane];
    float n0 = __int_as_float(e0.y), n1 = __int_as_float(e1.y);
    float n2 = __int_as_float(e2.y), n3 = __int_as_float(e3.y);
    float2 f0a = __half22float2(*(__half2*)&u0.x), f0b = __half22float2(*(__half2*)&u0.y);
    float2 f1a = __half22float2(*(__half2*)&u1.x), f1b = __half22float2(*(__half2*)&u1.y);
    float2 f2a = __half22float2(*(__half2*)&u2.x), f2b = __half22float2(*(__half2*)&u2.y);
    float2 f3a = __half22float2(*(__half2*)&u3.x), f3b = __half22float2(*(__half2*)&u3.y);
    a0x = fmaf(n0, f0a.x, a0x); a0y = fmaf(n0, f0a.y, a0y);
    a0z = fmaf(n0, f0b.x, a0z); a0w = fmaf(n0, f0b.y, a0w);
    a1x = fmaf(n1, f1a.x, a1x); a1y = fmaf(n1, f1a.y, a1y);
    a1z = fmaf(n1, f1b.x, a1z); a1w = fmaf(n1, f1b.y, a1w);
    a0x = fmaf(n2, f2a.x, a0x); a0y = fmaf(n2, f2a.y, a0y);
    a0z = fmaf(n2, f2b.x, a0z); a0w = fmaf(n2, f2b.y, a0w);
    a1x = fmaf(n3, f3a.x, a1x); a1y = fmaf(n3, f3a.y, a1y);
    a1z = fmaf(n3, f3b.x, a1z); a1w = fmaf(n3, f3b.y, a1w);
  }
  for (; p < end; ++p) {
    int2 pr = epair[p];
    float nw = __int_as_float(pr.y);
    uint2 u = xh[(size_t)pr.x * LPN + lane];
    float2 fa = __half22float2(*(__half2*)&u.x), fb = __half22float2(*(__half2*)&u.y);
    a0x = fmaf(nw, fa.x, a0x); a0y = fmaf(nw, fa.y, a0y);
    a0z = fmaf(nw, fb.x, a0z); a0w = fmaf(nw, fb.y, a0w);
  }
  float di = dinv[node];
  float sw = di * di;
  uint2 su = xh[(size_t)node * LPN + lane];   // fp16 self row
  float2 sa = __half22float2(*(__half2*)&su.x), sb = __half22float2(*(__half2*)&su.y);
  a0x = fmaf(sw, sa.x, a0x); a0y = fmaf(sw, sa.y, a0y);
  a0z = fmaf(sw, sb.x, a0z); a0w = fmaf(sw, sb.y, a0w);
  float4 b = ((const float4*)bias)[lane];
  float ox = a0x + a1x + b.x;
  float oy = a0y + a1y + b.y;
  float oz = a0z + a1z + b.z;
  float ow = a0w + a1w + b.w;
  if (RELU) {
    ox = fmaxf(ox, 0.f); oy = fmaxf(oy, 0.f);
    oz = fmaxf(oz, 0.f); ow = fmaxf(ow, 0.f);
  }
  ((float4*)out)[(size_t)node * LPN + lane] = make_float4(ox, oy, oz, ow);
}

// ---------------------------------------------------------------------------
extern "C" void kernel_launch(void* const* d_in, const int* in_sizes, int n_in,
                              void* d_out, int out_size, void* d_ws, size_t ws_size,
                              hipStream_t stream) {
  const float* x  = (const float*)d_in[0];
  const int*   ei = (const int*)d_in[1];     // int32, [2,E] flat
  const float* ew = (const float*)d_in[2];
  const float* W1 = (const float*)d_in[3];
  const float* b1 = (const float*)d_in[4];
  const float* W2 = (const float*)d_in[5];
  const float* b2 = (const float*)d_in[6];
  const float* W3 = (const float*)d_in[7];
  const float* b3 = (const float*)d_in[8];

  const int N = in_sizes[0] / 128;           // 100000
  const int E = in_sizes[2];                 // 1600000

  // workspace carve (256B aligned)
  char* ws = (char*)d_ws;
  size_t off = 0;
  auto carve = [&](size_t bytes) -> void* {
    void* p = ws + off;
    off += (bytes + 255) & ~(size_t)255;
    return p;
  };
  unsigned long long* packed = (unsigned long long*)carve((size_t)N * 8);
  int*   fillc   = (int*)carve((size_t)N * 4);
  float* dinv    = (float*)carve((size_t)N * 4);
  int*   row_ptr = (int*)carve((size_t)(N + 1) * 4);
  int*   parts   = (int*)carve(256 * 4);
  int2*  epair   = (int2*)carve((size_t)E * 8);
  float* bufF    = (float*)carve((size_t)N * 128 * 4);                 // fp32 h
  unsigned short* bufH = (unsigned short*)carve((size_t)N * 128 * 2);  // fp16 xw
  (void)ws_size; (void)n_in; (void)out_size;

  const int nThreads = 256;
  int gN  = (N + nThreads - 1) / nThreads;
  int gE  = (E + nThreads - 1) / nThreads;
  int nb  = (N + 1023) / 1024;               // scan blocks (98)

  // --- graph preprocessing (shared across the 3 layers) ---
  hipMemsetAsync(packed, 0, (size_t)N * 8, stream);
  hipMemsetAsync(fillc, 0, (size_t)N * 4, stream);
  edge_pass_kernel<<<gE, nThreads, 0, stream>>>(ei, ew, packed, E);
  dinv_kernel<<<gN, nThreads, 0, stream>>>(packed, dinv, N);
  scanA<<<nb, 1024, 0, stream>>>(packed, row_ptr, parts, N);
  scanB<<<1, 128, 0, stream>>>(parts, nb);
  scanC<<<nb, 1024, 0, stream>>>(row_ptr, parts, N);
  fill_kernel<<<gE, nThreads, 0, stream>>>(ei, ew, dinv, row_ptr, fillc, epair, E);

  const int gRows = (N + 127) / 128;         // 782 row-blocks (128 thr each)
  int gAgg128 = (N * 32 + nThreads - 1) / nThreads;
  int gAgg64  = (N * 16 + nThreads - 1) / nThreads;

  // --- layer 1: xw1 = fp16(x@W1) -> bufH; aggregate+bias+relu -> bufF ---
  gemm_rows_kernel<64><<<dim3(gRows, 2), 128, 0, stream>>>(x, W1, bufH, N, 128);
  agg_kernel<128, true><<<gAgg128, nThreads, 0, stream>>>(bufH, row_ptr, epair, dinv, b1, bufF, N);

  // --- layer 2 (bufF -> bufH -> bufF) ---
  gemm_rows_kernel<64><<<dim3(gRows, 2), 128, 0, stream>>>(bufF, W2, bufH, N, 128);
  agg_kernel<128, true><<<gAgg128, nThreads, 0, stream>>>(bufH, row_ptr, epair, dinv, b2, bufF, N);

  // --- layer 3 (64-wide, no relu) -> d_out ---
  gemm_rows_kernel<64><<<dim3(gRows, 1), 128, 0, stream>>>(bufF, W3, bufH, N, 64);
  agg_kernel<64, false><<<gAgg64, nThreads, 0, stream>>>(bufH, row_ptr, epair, dinv, b3, (float*)d_out, N);
}